// Round 9
// baseline (1184.595 us; speedup 1.0000x reference)
//
#include <hip/hip_runtime.h>
#include <hip/hip_bf16.h>
#include <math.h>

// Problem constants: V=96, D=128, T=64, H=8, HD=16, FF=512, L=4, B=4096
#define NTHR 512

typedef __attribute__((ext_vector_type(8))) short bf16x8;
typedef __attribute__((ext_vector_type(4))) short bf16x4;
typedef __attribute__((ext_vector_type(4))) float f32x4;

#define MFMA32(a, b, c) __builtin_amdgcn_mfma_f32_16x16x32_bf16((a), (b), (c), 0, 0, 0)

#if defined(__has_builtin)
#if __has_builtin(__builtin_amdgcn_mfma_f32_16x16x16bf16_1k)
#define HAVE_MFMA16 1
#endif
#endif
#ifdef HAVE_MFMA16
#define MFMA16(a, b, c) __builtin_amdgcn_mfma_f32_16x16x16bf16_1k((a), (b), (c), 0, 0, 0)
#else
__device__ __forceinline__ f32x4 mfma16_fb(bf16x4 a, bf16x4 b, f32x4 c) {
  asm volatile("s_nop 1\n\tv_mfma_f32_16x16x16_bf16 %0, %1, %2, %0\n\ts_nop 7\n\ts_nop 7"
               : "+v"(c) : "v"(a), "v"(b));
  return c;
}
#define MFMA16(a, b, c) mfma16_fb((a), (b), (c))
#endif

// ---- workspace layout (bf16 element offsets) ----
#define WS_EMB 0                      // [96][128]
#define WS_WQ  12288                  // 4x[128][128]
#define WS_WK  (WS_WQ + 65536)
#define WS_WV  (WS_WK + 65536)
#define WS_WO  (WS_WV + 65536)
#define WS_W1  (WS_WO + 65536)        // 4x[512][128]
#define WS_W2  (WS_W1 + 262144)       // 4x[128][512]
#define WS_END (WS_W2 + 262144)

__device__ __forceinline__ short f2bf(float f) {
  union { __hip_bfloat16 h; unsigned short s; } u;
  u.h = __float2bfloat16(f);
  return (short)u.s;
}
__device__ __forceinline__ bf16x4 pk4(f32x4 v) {
  bf16x4 r;
  r[0] = f2bf(v[0]); r[1] = f2bf(v[1]); r[2] = f2bf(v[2]); r[3] = f2bf(v[3]);
  return r;
}
__device__ __forceinline__ float gelu1(float x) {
  float y = x * __builtin_fmaf(0.0356774081f, x * x, 0.7978845608f);
  return x * __builtin_amdgcn_rcpf(1.f + exp2f(-2.885390082f * y));
}

// XOR chunk-swizzle (16B chunks within a row): logical col -> physical short index.
// Row stride is a multiple of 128B so banks are determined solely by the swizzled
// chunk -> b128 reads (16 lanes spanning 16 rows at one column) become conflict-free.
__device__ __forceinline__ int xn_idx(int r, int col) {   // sXn: stride 128 shorts
  return r * 128 + ((((col >> 3) ^ (r & 7))) << 3) + (col & 7);
}
__device__ __forceinline__ int h_idx(int r, int col) {    // sH: stride 512 shorts
  return r * 512 + ((((col >> 3) ^ (r & 7))) << 3) + (col & 7);
}

__global__ void prep_weights(const float* __restrict__ tok_emb,
                             const float* __restrict__ Wq, const float* __restrict__ Wk,
                             const float* __restrict__ Wv, const float* __restrict__ Wo,
                             const float* __restrict__ W1, const float* __restrict__ W2,
                             short* __restrict__ wsb) {
  int i = blockIdx.x * NTHR + threadIdx.x;
  if (i < 12288) {                       // tok_emb [96][128]
    int n = i >> 7, k = i & 127;
    wsb[WS_EMB + (k >> 3) * 768 + n * 8 + (k & 7)] = f2bf(tok_emb[i]);
    return;
  }
  i -= 12288;
  if (i < 262144) {                      // Wq,Wk,Wv,Wo: [4][128][128] each
    int tensor = i >> 16;
    int rem = i & 65535;
    int l = rem >> 14;
    int w = rem & 16383;
    int n = w >> 7, k = w & 127;
    const float* src = tensor == 0 ? Wq : tensor == 1 ? Wk : tensor == 2 ? Wv : Wo;
    wsb[WS_WQ + tensor * 65536 + l * 16384 + (k >> 3) * 1024 + n * 8 + (k & 7)] =
        f2bf(src[rem]);
    return;
  }
  i -= 262144;
  if (i < 262144) {                      // W1 [4][512][128]
    int l = i >> 16;
    int w = i & 65535;
    int n = w >> 7, k = w & 127;
    wsb[WS_W1 + l * 65536 + (k >> 3) * 4096 + n * 8 + (k & 7)] = f2bf(W1[i]);
    return;
  }
  i -= 262144;
  if (i < 262144) {                      // W2 [4][128][512]
    int l = i >> 16;
    int w = i & 65535;
    int n = w >> 9, k = w & 511;
    wsb[WS_W2 + l * 65536 + (k >> 3) * 1024 + n * 8 + (k & 7)] = f2bf(W2[i]);
  }
}

// LN: 8 threads/row, f32x4 loads from sX (stride 132), swizzled bf16x4 stores to sXn.
__device__ __forceinline__ void layernorm(const float* __restrict__ sXl,
                                          short* __restrict__ dstl,
                                          const float* __restrict__ g,
                                          const float* __restrict__ be, int tid) {
  int r = tid >> 3, t8 = tid & 7;
  const f32x4* row = (const f32x4*)(sXl + r * 132 + t8 * 16);
  f32x4 v[4];
  float s = 0.f, s2 = 0.f;
#pragma unroll
  for (int j = 0; j < 4; ++j) {
    v[j] = row[j];
#pragma unroll
    for (int c = 0; c < 4; ++c) { s += v[j][c]; s2 += v[j][c] * v[j][c]; }
  }
  s  += __shfl_xor(s, 1, 64);  s  += __shfl_xor(s, 2, 64);  s  += __shfl_xor(s, 4, 64);
  s2 += __shfl_xor(s2, 1, 64); s2 += __shfl_xor(s2, 2, 64); s2 += __shfl_xor(s2, 4, 64);
  float mean = s * 0.0078125f;
  float rs = rsqrtf(s2 * 0.0078125f - mean * mean + 1e-5f);
  const f32x4* gp = (const f32x4*)(g + t8 * 16);
  const f32x4* bp = (const f32x4*)(be + t8 * 16);
#pragma unroll
  for (int j = 0; j < 4; ++j) {
    f32x4 gg = gp[j], bb = bp[j], o;
#pragma unroll
    for (int c = 0; c < 4; ++c) o[c] = (v[j][c] - mean) * rs * gg[c] + bb[c];
    *(bf16x4*)(dstl + xn_idx(r, t8 * 16 + j * 4)) = pk4(o);
  }
}

// One block per sequence, 8 waves, wave = head. R2 structure (880us baseline) +
// bank-conflict fixes (XOR-swizzled sXn/sH, strides 140/76 for sQ/sK/sVT) +
// causal tile-skip in attention. 2 waves/SIMD is structural (total regs ~200);
// (512,2) is the only spill-free config (R3-R8 evidence).
__global__ __launch_bounds__(512, 2)
void lm_forward(const int* __restrict__ idx, const int* __restrict__ targets,
                const float* __restrict__ tok_emb, const float* __restrict__ pos_emb,
                const float* __restrict__ bo, const float* __restrict__ ln1_g,
                const float* __restrict__ ln1_b, const float* __restrict__ ln2_g,
                const float* __restrict__ ln2_b, const float* __restrict__ b1,
                const float* __restrict__ b2, const float* __restrict__ lnf_g,
                const float* __restrict__ lnf_b, const float* __restrict__ lm_b,
                const short* __restrict__ wsb, float* __restrict__ out,
                float* __restrict__ loss_part) {
  __shared__ __align__(16) char smem[115968];
  float* sX  = (float*)smem;                 // [64][132] f32 residual
  short* sXn = (short*)(smem + 33792);       // [64][128] bf16 swizzled (LN out / att out)
  char*  Rg  = smem + 50176;                 // overlapped region (65536 B)
  short* sQ  = (short*)Rg;                   // [64][140]
  short* sK  = (short*)(Rg + 17920);         // [64][140]
  short* sVT = (short*)(Rg + 35840);         // [128][76] V^T
  short* sH  = (short*)Rg;                   // [64][512] swizzled (FF hidden)
  float* sL  = (float*)Rg;                   // [64][100] logits
  float* sRed = (float*)(smem + 115712);

  const int b = blockIdx.x;
  const int tid = threadIdx.x;
  const int wave = tid >> 6;
  const int lane = tid & 63;
  const int lr = lane & 15;
  const int lg = lane >> 4;
  const f32x4 fz = {0.f, 0.f, 0.f, 0.f};
  const float KSC = 0.360673760f;            // 0.25 * log2(e)

  // ---- embedding ----
#pragma unroll
  for (int k = 0; k < 4; ++k) {
    int e = (tid + k * 512) * 4;
    int t = e >> 7, d = e & 127;
    f32x4 te = *(const f32x4*)(tok_emb + idx[b * 64 + t] * 128 + d);
    f32x4 pe = *(const f32x4*)(pos_emb + e);
    *(f32x4*)(sX + t * 132 + d) = te + pe;
  }
  __syncthreads();

#pragma unroll 1
  for (int l = 0; l < 4; ++l) {
    layernorm(sX, sXn, ln1_g + l * 128, ln1_b + l * 128, tid);
    __syncthreads();

    // ---- QKV single pass (12 acc, max ILP). Q^T,K^T transposed; V normal ----
    {
      const short* wq = wsb + WS_WQ + l * 16384;
      const short* wk = wsb + WS_WK + l * 16384;
      const short* wv = wsb + WS_WV + l * 16384;
      f32x4 aq[4], ak[4], av[4];
#pragma unroll
      for (int n = 0; n < 4; ++n) { aq[n] = fz; ak[n] = fz; av[n] = fz; }
#pragma unroll
      for (int ks = 0; ks < 4; ++ks) {
        bf16x8 xf[4];
#pragma unroll
        for (int n = 0; n < 4; ++n)
          xf[n] = *(const bf16x8*)(sXn + xn_idx(16 * n + lr, ks * 32 + lg * 8));
        int wo_ = (ks * 4 + lg) * 1024 + (wave * 16 + lr) * 8;
        bf16x8 qw = *(const bf16x8*)(wq + wo_);
        bf16x8 kw = *(const bf16x8*)(wk + wo_);
        bf16x8 vw = *(const bf16x8*)(wv + wo_);
#pragma unroll
        for (int n = 0; n < 4; ++n) {
          aq[n] = MFMA32(qw, xf[n], aq[n]);
          ak[n] = MFMA32(kw, xf[n], ak[n]);
          av[n] = MFMA32(xf[n], vw, av[n]);
        }
      }
#pragma unroll
      for (int n = 0; n < 4; ++n) {
        *(bf16x4*)(sQ + (n * 16 + lr) * 140 + wave * 16 + lg * 4) = pk4(aq[n] * KSC);
        *(bf16x4*)(sK + (n * 16 + lr) * 140 + wave * 16 + lg * 4) = pk4(ak[n]);
        bf16x4 vv = pk4(av[n]);
        int col = wave * 16 + lr;          // token col of av (normal orientation)
#pragma unroll
        for (int r = 0; r < 4; ++r)
          sVT[col * 76 + n * 16 + lg * 4 + r] = vv[r];
      }
    }
    __syncthreads();

    // ---- attention: wave = head, in-register softmax, causal tile-skip ----
    {
      const int h = wave;
      bf16x4 kf[4], qf[4], vfr[4];
#pragma unroll
      for (int m = 0; m < 4; ++m) {
        kf[m] = *(const bf16x4*)(sK + (m * 16 + lr) * 140 + h * 16 + lg * 4);
        vfr[m] = *(const bf16x4*)(sVT + (h * 16 + lr) * 76 + m * 16 + lg * 4);
      }
#pragma unroll
      for (int n = 0; n < 4; ++n)
        qf[n] = *(const bf16x4*)(sQ + (n * 16 + lr) * 140 + h * 16 + lg * 4);
      f32x4 sc[4][4];                        // upper triangle (m<=n) used
#pragma unroll
      for (int n = 0; n < 4; ++n)
#pragma unroll
        for (int m = 0; m <= n; ++m)
          sc[m][n] = MFMA16(kf[m], qf[n], fz);
#pragma unroll
      for (int n = 0; n < 4; ++n) {
        // diagonal tile mask: key lg*4+r > query lr
#pragma unroll
        for (int r = 0; r < 4; ++r)
          if (lg * 4 + r > lr) sc[n][n][r] = -1e30f;
        float mx = -1e30f;
#pragma unroll
        for (int m = 0; m <= n; ++m)
#pragma unroll
          for (int r = 0; r < 4; ++r) mx = fmaxf(mx, sc[m][n][r]);
        mx = fmaxf(mx, __shfl_xor(mx, 16, 64));
        mx = fmaxf(mx, __shfl_xor(mx, 32, 64));
        float sum = 0.f;
#pragma unroll
        for (int m = 0; m <= n; ++m)
#pragma unroll
          for (int r = 0; r < 4; ++r) {
            float p = exp2f(sc[m][n][r] - mx);
            sc[m][n][r] = p;
            sum += p;
          }
        sum += __shfl_xor(sum, 16, 64);
        sum += __shfl_xor(sum, 32, 64);
        float rinv = __builtin_amdgcn_rcpf(sum);
        f32x4 ao = fz;
#pragma unroll
        for (int m = 0; m <= n; ++m) {
          bf16x4 pf = pk4(sc[m][n] * rinv);
          ao = MFMA16(vfr[m], pf, ao);
        }
        *(bf16x4*)(sXn + xn_idx(16 * n + lr, h * 16 + lg * 4)) = pk4(ao);
      }
    }
    __syncthreads();

    // ---- Wo + residual ----
    {
      const short* wo = wsb + WS_WO + l * 16384;
      f32x4 ac[4];
#pragma unroll
      for (int n = 0; n < 4; ++n) ac[n] = fz;
#pragma unroll
      for (int ks = 0; ks < 4; ++ks) {
        bf16x8 wf = *(const bf16x8*)(wo + (ks * 4 + lg) * 1024 + (wave * 16 + lr) * 8);
#pragma unroll
        for (int n = 0; n < 4; ++n) {
          bf16x8 af = *(const bf16x8*)(sXn + xn_idx(16 * n + lr, ks * 32 + lg * 8));
          ac[n] = MFMA32(wf, af, ac[n]);
        }
      }
      f32x4 bo4 = *(const f32x4*)(bo + l * 128 + wave * 16 + lg * 4);
#pragma unroll
      for (int n = 0; n < 4; ++n) {
        f32x4* px = (f32x4*)(sX + (n * 16 + lr) * 132 + wave * 16 + lg * 4);
        *px = *px + ac[n] + bo4;
      }
    }
    __syncthreads();

    layernorm(sX, sXn, ln2_g + l * 128, ln2_b + l * 128, tid);
    __syncthreads();

    // ---- FF unchunked (64-acc FF1), one barrier pair ----
    {
      const short* w1 = wsb + WS_W1 + l * 65536;
      const short* w2 = wsb + WS_W2 + l * 65536;
      f32x4 a1[4][4];
#pragma unroll
      for (int g = 0; g < 4; ++g)
#pragma unroll
        for (int n = 0; n < 4; ++n) a1[g][n] = fz;
#pragma unroll
      for (int ks = 0; ks < 4; ++ks) {
        bf16x8 xf[4];
#pragma unroll
        for (int n = 0; n < 4; ++n)
          xf[n] = *(const bf16x8*)(sXn + xn_idx(16 * n + lr, ks * 32 + lg * 8));
#pragma unroll
        for (int g = 0; g < 4; ++g) {
          bf16x8 wf = *(const bf16x8*)(w1 + (ks * 4 + lg) * 4096 +
                                       (wave * 64 + g * 16 + lr) * 8);
#pragma unroll
          for (int n = 0; n < 4; ++n) a1[g][n] = MFMA32(wf, xf[n], a1[g][n]);
        }
      }
#pragma unroll
      for (int g = 0; g < 4; ++g) {
        f32x4 b1v = *(const f32x4*)(b1 + l * 512 + wave * 64 + g * 16 + lg * 4);
#pragma unroll
        for (int n = 0; n < 4; ++n) {
          f32x4 hv;
#pragma unroll
          for (int r = 0; r < 4; ++r) hv[r] = gelu1(a1[g][n][r] + b1v[r]);
          *(bf16x4*)(sH + h_idx(16 * n + lr, wave * 64 + g * 16 + lg * 4)) = pk4(hv);
        }
      }
      __syncthreads();
      f32x4 a2[4];
#pragma unroll
      for (int n = 0; n < 4; ++n) a2[n] = fz;
#pragma unroll
      for (int ks = 0; ks < 16; ++ks) {
        bf16x8 wf = *(const bf16x8*)(w2 + (ks * 4 + lg) * 1024 + (wave * 16 + lr) * 8);
#pragma unroll
        for (int n = 0; n < 4; ++n) {
          bf16x8 hf = *(const bf16x8*)(sH + h_idx(16 * n + lr, ks * 32 + lg * 8));
          a2[n] = MFMA32(wf, hf, a2[n]);
        }
      }
      f32x4 b2v = *(const f32x4*)(b2 + l * 128 + wave * 16 + lg * 4);
#pragma unroll
      for (int n = 0; n < 4; ++n) {
        f32x4* px = (f32x4*)(sX + (n * 16 + lr) * 132 + wave * 16 + lg * 4);
        *px = *px + a2[n] + b2v;
      }
    }
    __syncthreads();
  }

  // ---- final LN ----
  layernorm(sX, sXn, lnf_g, lnf_b, tid);
  __syncthreads();

  // ---- logits (waves 0..5 cover 96 cols) ----
  if (wave < 6) {
    f32x4 al[4];
#pragma unroll
    for (int n = 0; n < 4; ++n) al[n] = fz;
#pragma unroll
    for (int ks = 0; ks < 4; ++ks) {
      bf16x8 ef = *(const bf16x8*)(wsb + WS_EMB + (ks * 4 + lg) * 768 +
                                   (wave * 16 + lr) * 8);
#pragma unroll
      for (int n = 0; n < 4; ++n) {
        bf16x8 xf = *(const bf16x8*)(sXn + xn_idx(16 * n + lr, ks * 32 + lg * 8));
        al[n] = MFMA32(ef, xf, al[n]);
      }
    }
    f32x4 lb = *(const f32x4*)(lm_b + wave * 16 + lg * 4);
#pragma unroll
    for (int n = 0; n < 4; ++n) {
      f32x4 v = al[n] + lb;
      int token = n * 16 + lr;
      *(f32x4*)(out + ((size_t)b * 64 + token) * 96 + wave * 16 + lg * 4) = v;
      *(f32x4*)(sL + token * 100 + wave * 16 + lg * 4) = v;
    }
  }
  __syncthreads();

  // ---- per-row cross-entropy ----
  {
    int r = tid >> 3, t8 = tid & 7;
    const float* lrow = sL + r * 100 + t8 * 12;
    float mx = -1e30f;
#pragma unroll
    for (int j = 0; j < 12; ++j) mx = fmaxf(mx, lrow[j]);
    mx = fmaxf(mx, __shfl_xor(mx, 1, 64));
    mx = fmaxf(mx, __shfl_xor(mx, 2, 64));
    mx = fmaxf(mx, __shfl_xor(mx, 4, 64));
    float sum = 0.f;
#pragma unroll
    for (int j = 0; j < 12; ++j) sum += __expf(lrow[j] - mx);
    sum += __shfl_xor(sum, 1, 64);
    sum += __shfl_xor(sum, 2, 64);
    sum += __shfl_xor(sum, 4, 64);
    if (t8 == 0) {
      float lse = logf(sum) + mx;
      sRed[r] = lse - sL[r * 100 + targets[b * 64 + r]];
    }
  }
  __syncthreads();
  if (wave == 0) {
    float v = sRed[lane];
#pragma unroll
    for (int m = 32; m >= 1; m >>= 1) v += __shfl_xor(v, m, 64);
    if (lane == 0) loss_part[b] = v;
  }
}

__global__ void loss_reduce(const float* __restrict__ loss_part, float* __restrict__ out_loss) {
  __shared__ float red[256];
  int t = threadIdx.x;
  float s = 0.f;
  for (int i = t; i < 4096; i += 256) s += loss_part[i];
  red[t] = s;
  __syncthreads();
  for (int k = 128; k >= 1; k >>= 1) {
    if (t < k) red[t] += red[t + k];
    __syncthreads();
  }
  if (t == 0) out_loss[0] = red[0] * (1.f / 262144.f);
}

extern "C" void kernel_launch(void* const* d_in, const int* in_sizes, int n_in,
                              void* d_out, int out_size, void* d_ws, size_t ws_size,
                              hipStream_t stream) {
  (void)in_sizes; (void)n_in; (void)ws_size;
  const int* idx      = (const int*)d_in[0];
  const int* targets  = (const int*)d_in[1];
  const float* tok_emb = (const float*)d_in[2];
  const float* pos_emb = (const float*)d_in[3];
  const float* Wq = (const float*)d_in[4];
  const float* Wk = (const float*)d_in[5];
  const float* Wv = (const float*)d_in[6];
  const float* Wo = (const float*)d_in[7];
  const float* bo = (const float*)d_in[8];
  const float* ln1_g = (const float*)d_in[9];
  const float* ln1_b = (const float*)d_in[10];
  const float* ln2_g = (const float*)d_in[11];
  const float* ln2_b = (const float*)d_in[12];
  const float* W1 = (const float*)d_in[13];
  const float* b1 = (const float*)d_in[14];
  const float* W2 = (const float*)d_in[15];
  const float* b2 = (const float*)d_in[16];
  const float* lnf_g = (const float*)d_in[17];
  const float* lnf_b = (const float*)d_in[18];
  const float* lm_b = (const float*)d_in[19];

  short* wsb = (short*)d_ws;
  float* loss_part = (float*)((char*)d_ws + (size_t)WS_END * 2);
  float* out = (float*)d_out;

  prep_weights<<<1560, NTHR, 0, stream>>>(tok_emb, Wq, Wk, Wv, Wo, W1, W2, wsb);
  lm_forward<<<4096, NTHR, 0, stream>>>(idx, targets, tok_emb, pos_emb, bo,
                                        ln1_g, ln1_b, ln2_g, ln2_b, b1, b2,
                                        lnf_g, lnf_b, lm_b, wsb, out, loss_part);
  loss_reduce<<<1, 256, 0, stream>>>(loss_part, out + (out_size - 1));
}

// Round 10
// 869.409 us; speedup vs baseline: 1.3625x; 1.3625x over previous
//
#include <hip/hip_runtime.h>
#include <hip/hip_bf16.h>
#include <math.h>

// Problem constants: V=96, D=128, T=64, H=8, HD=16, FF=512, L=4, B=4096
#define PREP_THR 512

typedef __attribute__((ext_vector_type(8))) short bf16x8;
typedef __attribute__((ext_vector_type(4))) short bf16x4;
typedef __attribute__((ext_vector_type(4))) float f32x4;

#define MFMA32(a, b, c) __builtin_amdgcn_mfma_f32_16x16x32_bf16((a), (b), (c), 0, 0, 0)

#if defined(__has_builtin)
#if __has_builtin(__builtin_amdgcn_mfma_f32_16x16x16bf16_1k)
#define HAVE_MFMA16 1
#endif
#endif
#ifdef HAVE_MFMA16
#define MFMA16(a, b, c) __builtin_amdgcn_mfma_f32_16x16x16bf16_1k((a), (b), (c), 0, 0, 0)
#else
__device__ __forceinline__ f32x4 mfma16_fb(bf16x4 a, bf16x4 b, f32x4 c) {
  asm volatile("s_nop 1\n\tv_mfma_f32_16x16x16_bf16 %0, %1, %2, %0\n\ts_nop 7\n\ts_nop 7"
               : "+v"(c) : "v"(a), "v"(b));
  return c;
}
#define MFMA16(a, b, c) mfma16_fb((a), (b), (c))
#endif

// ---- workspace layout (bf16 element offsets) ----
// weights pre-converted to bf16, swizzled [K/8][N][8]: dst[(k>>3)*N*8 + n*8 + (k&7)] = W[n][k]
#define WS_EMB 0                      // [96][128]
#define WS_WQ  12288                  // 4x[128][128]
#define WS_WK  (WS_WQ + 65536)
#define WS_WV  (WS_WK + 65536)
#define WS_WO  (WS_WV + 65536)
#define WS_W1  (WS_WO + 65536)        // 4x[512][128]
#define WS_W2  (WS_W1 + 262144)       // 4x[128][512]
#define WS_END (WS_W2 + 262144)

__device__ __forceinline__ short f2bf(float f) {
  union { __hip_bfloat16 h; unsigned short s; } u;
  u.h = __float2bfloat16(f);
  return (short)u.s;
}
__device__ __forceinline__ bf16x4 pk4(f32x4 v) {
  bf16x4 r;
  r[0] = f2bf(v[0]); r[1] = f2bf(v[1]); r[2] = f2bf(v[2]); r[3] = f2bf(v[3]);
  return r;
}
__device__ __forceinline__ float gelu1(float x) {
  float y = x * __builtin_fmaf(0.0356774081f, x * x, 0.7978845608f);
  return x * __builtin_amdgcn_rcpf(1.f + exp2f(-2.885390082f * y));
}

__global__ void prep_weights(const float* __restrict__ tok_emb,
                             const float* __restrict__ Wq, const float* __restrict__ Wk,
                             const float* __restrict__ Wv, const float* __restrict__ Wo,
                             const float* __restrict__ W1, const float* __restrict__ W2,
                             short* __restrict__ wsb) {
  int i = blockIdx.x * PREP_THR + threadIdx.x;
  if (i < 12288) {                       // tok_emb [96][128]
    int n = i >> 7, k = i & 127;
    wsb[WS_EMB + (k >> 3) * 768 + n * 8 + (k & 7)] = f2bf(tok_emb[i]);
    return;
  }
  i -= 12288;
  if (i < 262144) {                      // Wq,Wk,Wv,Wo: [4][128][128] each
    int tensor = i >> 16;
    int rem = i & 65535;
    int l = rem >> 14;
    int w = rem & 16383;
    int n = w >> 7, k = w & 127;
    const float* src = tensor == 0 ? Wq : tensor == 1 ? Wk : tensor == 2 ? Wv : Wo;
    wsb[WS_WQ + tensor * 65536 + l * 16384 + (k >> 3) * 1024 + n * 8 + (k & 7)] =
        f2bf(src[rem]);
    return;
  }
  i -= 262144;
  if (i < 262144) {                      // W1 [4][512][128]
    int l = i >> 16;
    int w = i & 65535;
    int n = w >> 7, k = w & 127;
    wsb[WS_W1 + l * 65536 + (k >> 3) * 4096 + n * 8 + (k & 7)] = f2bf(W1[i]);
    return;
  }
  i -= 262144;
  if (i < 262144) {                      // W2 [4][128][512]
    int l = i >> 16;
    int w = i & 65535;
    int n = w >> 9, k = w & 511;
    wsb[WS_W2 + l * 65536 + (k >> 3) * 1024 + n * 8 + (k & 7)] = f2bf(W2[i]);
  }
}

// One block per sequence, 256 threads = 4 waves; 2 blocks/CU (LDS 53.5 KB).
// Wave owns 32 dims (2 heads). Residual X^T in regs: x[cg][n][r] =
// X^T[wave*32+cg*16+lg*4+r][16n+lr]. Rationale (R2..R9 evidence): 8-wave blocks
// serialize on lockstep barriers at 2 waves/SIMD; register knobs for >8 waves/CU
// all spill (budget collapses to 64). 4-wave blocks keep the 256-reg/wave budget
// AND give two INDEPENDENT barrier domains per CU -> stalls overlap.
__global__ __launch_bounds__(256, 2)
void lm_forward(const int* __restrict__ idx, const int* __restrict__ targets,
                const float* __restrict__ tok_emb, const float* __restrict__ pos_emb,
                const float* __restrict__ bo, const float* __restrict__ ln1_g,
                const float* __restrict__ ln1_b, const float* __restrict__ ln2_g,
                const float* __restrict__ ln2_b, const float* __restrict__ b1,
                const float* __restrict__ b2, const float* __restrict__ lnf_g,
                const float* __restrict__ lnf_b, const float* __restrict__ lm_b,
                const short* __restrict__ wsb, float* __restrict__ out,
                float* __restrict__ loss_part) {
  __shared__ __align__(16) short sXn[64 * 136];      // 17408 B (LN out)
  __shared__ __align__(16) char region[33792];       // sAtt[64][136] / sH[64][264] / sL[64][100]f32
  __shared__ __align__(16) float sPart[4 * 64 * 2];  // 2048 B LN partials
  __shared__ float sRed[64];
  short* sAtt = (short*)region;
  short* sH = (short*)region;
  float* sL = (float*)region;

  const int b = blockIdx.x;
  const int tid = threadIdx.x;
  const int wave = tid >> 6;       // 0..3
  const int lane = tid & 63;
  const int lr = lane & 15;
  const int lg = lane >> 4;
  const f32x4 fz = {0.f, 0.f, 0.f, 0.f};
  const float KSC = 0.360673760f;  // 0.25 * log2(e)

  // ---- embedding: residual regs (wave owns dims wave*32 .. +31) ----
  f32x4 x[2][4];
#pragma unroll
  for (int cg = 0; cg < 2; ++cg)
#pragma unroll
    for (int n = 0; n < 4; ++n) {
      int t = 16 * n + lr;
      int dim = wave * 32 + cg * 16 + lg * 4;
      int tk = idx[b * 64 + t];
      x[cg][n] = *(const f32x4*)(tok_emb + tk * 128 + dim) +
                 *(const f32x4*)(pos_emb + t * 128 + dim);
    }

  // LN on reg residual; 2 barriers; writes sXn.
  auto ln = [&](const float* g, const float* be) {
    float s[4], s2[4];
#pragma unroll
    for (int n = 0; n < 4; ++n) {
      float a = 0.f, a2 = 0.f;
#pragma unroll
      for (int cg = 0; cg < 2; ++cg)
#pragma unroll
        for (int r = 0; r < 4; ++r) {
          float v = x[cg][n][r];
          a += v; a2 += v * v;
        }
      s[n] = a; s2[n] = a2;
    }
#pragma unroll
    for (int n = 0; n < 4; ++n) {
      s[n] += __shfl_xor(s[n], 16, 64);  s[n] += __shfl_xor(s[n], 32, 64);
      s2[n] += __shfl_xor(s2[n], 16, 64); s2[n] += __shfl_xor(s2[n], 32, 64);
    }
    if (lg == 0) {
#pragma unroll
      for (int n = 0; n < 4; ++n) {
        float2 p; p.x = s[n]; p.y = s2[n];
        *(float2*)(sPart + (wave * 64 + 16 * n + lr) * 2) = p;
      }
    }
    __syncthreads();
    f32x4 g4[2], b4[2];
#pragma unroll
    for (int cg = 0; cg < 2; ++cg) {
      int dim = wave * 32 + cg * 16 + lg * 4;
      g4[cg] = *(const f32x4*)(g + dim);
      b4[cg] = *(const f32x4*)(be + dim);
    }
#pragma unroll
    for (int n = 0; n < 4; ++n) {
      float S = 0.f, S2 = 0.f;
#pragma unroll
      for (int w = 0; w < 4; ++w) {
        float2 p = *(const float2*)(sPart + (w * 64 + 16 * n + lr) * 2);
        S += p.x; S2 += p.y;
      }
      float mean = S * 0.0078125f;
      float rstd = rsqrtf(__builtin_fmaf(-mean, mean, S2 * 0.0078125f) + 1e-5f);
#pragma unroll
      for (int cg = 0; cg < 2; ++cg) {
        f32x4 o;
#pragma unroll
        for (int c = 0; c < 4; ++c)
          o[c] = __builtin_fmaf((x[cg][n][c] - mean) * rstd, g4[cg][c], b4[cg][c]);
        *(bf16x4*)(sXn + (16 * n + lr) * 136 + wave * 32 + cg * 16 + lg * 4) = pk4(o);
      }
    }
    __syncthreads();
  };

#pragma unroll 1
  for (int l = 0; l < 4; ++l) {
    ln(ln1_g + l * 128, ln1_b + l * 128);

    // ---- QKV + attention, per head (wave owns heads 2*wave, 2*wave+1) ----
    const short* wq = wsb + WS_WQ + l * 16384;
    const short* wk = wsb + WS_WK + l * 16384;
    const short* wv = wsb + WS_WV + l * 16384;
#pragma unroll
    for (int hs = 0; hs < 2; ++hs) {
      const int h = wave * 2 + hs;
      f32x4 aq[4], ak[4], av[4];
#pragma unroll
      for (int n = 0; n < 4; ++n) { aq[n] = fz; ak[n] = fz; av[n] = fz; }
#pragma unroll
      for (int ks = 0; ks < 4; ++ks) {
        bf16x8 xf[4];
#pragma unroll
        for (int n = 0; n < 4; ++n)
          xf[n] = *(const bf16x8*)(sXn + (16 * n + lr) * 136 + ks * 32 + lg * 8);
        int wo_ = (ks * 4 + lg) * 1024 + (h * 16 + lr) * 8;
        bf16x8 qw = *(const bf16x8*)(wq + wo_);
        bf16x8 kw = *(const bf16x8*)(wk + wo_);
        bf16x8 vw = *(const bf16x8*)(wv + wo_);
#pragma unroll
        for (int n = 0; n < 4; ++n) {
          aq[n] = MFMA32(qw, xf[n], aq[n]);
          ak[n] = MFMA32(kw, xf[n], ak[n]);
          av[n] = MFMA32(xf[n], vw, av[n]);
        }
      }
      bf16x4 qf[4], kf[4], vf[4];
#pragma unroll
      for (int n = 0; n < 4; ++n) {
        qf[n] = pk4(aq[n] * KSC);
        kf[n] = pk4(ak[n]);
        vf[n] = pk4(av[n]);
      }
      // in-register attention, causal tile-skip (verified R7)
      f32x4 sc[4][4];
#pragma unroll
      for (int n = 0; n < 4; ++n)
#pragma unroll
        for (int m = 0; m <= n; ++m)
          sc[m][n] = MFMA16(kf[m], qf[n], fz);
#pragma unroll
      for (int n = 0; n < 4; ++n) {
#pragma unroll
        for (int r = 0; r < 4; ++r)
          if (lg * 4 + r > lr) sc[n][n][r] = -1e30f;
        float mx = -1e30f;
#pragma unroll
        for (int m = 0; m <= n; ++m)
#pragma unroll
          for (int r = 0; r < 4; ++r) mx = fmaxf(mx, sc[m][n][r]);
        mx = fmaxf(mx, __shfl_xor(mx, 16, 64));
        mx = fmaxf(mx, __shfl_xor(mx, 32, 64));
        float sum = 0.f;
#pragma unroll
        for (int m = 0; m <= n; ++m)
#pragma unroll
          for (int r = 0; r < 4; ++r) {
            float p = exp2f(sc[m][n][r] - mx);
            sc[m][n][r] = p;
            sum += p;
          }
        sum += __shfl_xor(sum, 16, 64);
        sum += __shfl_xor(sum, 32, 64);
        float rinv = __builtin_amdgcn_rcpf(sum);
        f32x4 ao = fz;
#pragma unroll
        for (int m = 0; m <= n; ++m) {
          bf16x4 pf = pk4(sc[m][n] * rinv);
          ao = MFMA16(vf[m], pf, ao);
        }
        *(bf16x4*)(sAtt + (16 * n + lr) * 136 + h * 16 + lg * 4) = pk4(ao);
      }
    }
    __syncthreads();

    // ---- Wo + residual (cols wave*32..+31) ----
    {
      const short* wo = wsb + WS_WO + l * 16384;
      f32x4 ac[2][4];
#pragma unroll
      for (int cg = 0; cg < 2; ++cg)
#pragma unroll
        for (int n = 0; n < 4; ++n) ac[cg][n] = fz;
#pragma unroll
      for (int ks = 0; ks < 4; ++ks) {
        bf16x8 af[4];
#pragma unroll
        for (int n = 0; n < 4; ++n)
          af[n] = *(const bf16x8*)(sAtt + (16 * n + lr) * 136 + ks * 32 + lg * 8);
#pragma unroll
        for (int cg = 0; cg < 2; ++cg) {
          bf16x8 wf = *(const bf16x8*)(wo + (ks * 4 + lg) * 1024 +
                                       (wave * 32 + cg * 16 + lr) * 8);
#pragma unroll
          for (int n = 0; n < 4; ++n) ac[cg][n] = MFMA32(wf, af[n], ac[cg][n]);
        }
      }
#pragma unroll
      for (int cg = 0; cg < 2; ++cg) {
        f32x4 bo4 = *(const f32x4*)(bo + l * 128 + wave * 32 + cg * 16 + lg * 4);
#pragma unroll
        for (int n = 0; n < 4; ++n) x[cg][n] = x[cg][n] + ac[cg][n] + bo4;
      }
    }

    ln(ln2_g + l * 128, ln2_b + l * 128);

    // ---- FF: 2 hidden chunks of 256 (wave: 64 cols/chunk); a2 in regs ----
    {
      const short* w1 = wsb + WS_W1 + l * 65536;
      const short* w2 = wsb + WS_W2 + l * 65536;
      f32x4 a2[2][4];
#pragma unroll
      for (int cg = 0; cg < 2; ++cg)
#pragma unroll
        for (int n = 0; n < 4; ++n) a2[cg][n] = fz;
#pragma unroll 1
      for (int c = 0; c < 2; ++c) {
        f32x4 a1[4][4];
#pragma unroll
        for (int g = 0; g < 4; ++g)
#pragma unroll
          for (int n = 0; n < 4; ++n) a1[g][n] = fz;
#pragma unroll
        for (int ks = 0; ks < 4; ++ks) {
          bf16x8 xf[4];
#pragma unroll
          for (int n = 0; n < 4; ++n)
            xf[n] = *(const bf16x8*)(sXn + (16 * n + lr) * 136 + ks * 32 + lg * 8);
#pragma unroll
          for (int g = 0; g < 4; ++g) {
            bf16x8 wf = *(const bf16x8*)(w1 + (ks * 4 + lg) * 4096 +
                                         (c * 256 + wave * 64 + g * 16 + lr) * 8);
#pragma unroll
            for (int n = 0; n < 4; ++n) a1[g][n] = MFMA32(wf, xf[n], a1[g][n]);
          }
        }
#pragma unroll
        for (int g = 0; g < 4; ++g) {
          f32x4 b1v = *(const f32x4*)(b1 + l * 512 + c * 256 + wave * 64 + g * 16 + lg * 4);
#pragma unroll
          for (int n = 0; n < 4; ++n) {
            f32x4 hv;
#pragma unroll
            for (int r = 0; r < 4; ++r) hv[r] = gelu1(a1[g][n][r] + b1v[r]);
            *(bf16x4*)(sH + (16 * n + lr) * 264 + wave * 64 + g * 16 + lg * 4) = pk4(hv);
          }
        }
        __syncthreads();
#pragma unroll
        for (int ks = 0; ks < 8; ++ks) {
          bf16x8 hf[4];
#pragma unroll
          for (int n = 0; n < 4; ++n)
            hf[n] = *(const bf16x8*)(sH + (16 * n + lr) * 264 + ks * 32 + lg * 8);
#pragma unroll
          for (int cg = 0; cg < 2; ++cg) {
            bf16x8 wf = *(const bf16x8*)(w2 + (c * 32 + ks * 4 + lg) * 1024 +
                                         (wave * 32 + cg * 16 + lr) * 8);
#pragma unroll
            for (int n = 0; n < 4; ++n) a2[cg][n] = MFMA32(wf, hf[n], a2[cg][n]);
          }
        }
        if (c == 0) __syncthreads();
      }
#pragma unroll
      for (int cg = 0; cg < 2; ++cg) {
        f32x4 b2v = *(const f32x4*)(b2 + l * 128 + wave * 32 + cg * 16 + lg * 4);
#pragma unroll
        for (int n = 0; n < 4; ++n) x[cg][n] = x[cg][n] + a2[cg][n] + b2v;
      }
    }
  }

  // ---- final LN ----
  ln(lnf_g, lnf_b);

  // ---- logits: vocab tiles {wave} + {wave+4 if wave<2} ----
  {
    auto do_tile = [&](int vt) {
      f32x4 al[4];
#pragma unroll
      for (int n = 0; n < 4; ++n) al[n] = fz;
#pragma unroll
      for (int ks = 0; ks < 4; ++ks) {
        bf16x8 ef = *(const bf16x8*)(wsb + WS_EMB + (ks * 4 + lg) * 768 +
                                     (vt * 16 + lr) * 8);
#pragma unroll
        for (int n = 0; n < 4; ++n) {
          bf16x8 xf = *(const bf16x8*)(sXn + (16 * n + lr) * 136 + ks * 32 + lg * 8);
          al[n] = MFMA32(ef, xf, al[n]);
        }
      }
      f32x4 lb = *(const f32x4*)(lm_b + vt * 16 + lg * 4);
#pragma unroll
      for (int n = 0; n < 4; ++n) {
        f32x4 v = al[n] + lb;
        int t = 16 * n + lr;
        *(f32x4*)(out + ((size_t)b * 64 + t) * 96 + vt * 16 + lg * 4) = v;
        *(f32x4*)(sL + t * 100 + vt * 16 + lg * 4) = v;
      }
    };
    do_tile(wave);
    if (wave < 2) do_tile(wave + 4);
  }
  __syncthreads();

  // ---- per-row cross-entropy (4 threads/row, 24 cols each) ----
  {
    int r = tid >> 2, c4 = tid & 3;
    const float* lrow = sL + r * 100 + c4 * 24;
    float mx = -1e30f;
#pragma unroll
    for (int j = 0; j < 24; ++j) mx = fmaxf(mx, lrow[j]);
    mx = fmaxf(mx, __shfl_xor(mx, 1, 64));
    mx = fmaxf(mx, __shfl_xor(mx, 2, 64));
    float sum = 0.f;
#pragma unroll
    for (int j = 0; j < 24; ++j) sum += __expf(lrow[j] - mx);
    sum += __shfl_xor(sum, 1, 64);
    sum += __shfl_xor(sum, 2, 64);
    if (c4 == 0) {
      float lse = logf(sum) + mx;
      sRed[r] = lse - sL[r * 100 + targets[b * 64 + r]];
    }
  }
  __syncthreads();
  if (wave == 0) {
    float v = sRed[lane];
#pragma unroll
    for (int m = 32; m >= 1; m >>= 1) v += __shfl_xor(v, m, 64);
    if (lane == 0) loss_part[b] = v;
  }
}

__global__ void loss_reduce(const float* __restrict__ loss_part, float* __restrict__ out_loss) {
  __shared__ float red[256];
  int t = threadIdx.x;
  float s = 0.f;
  for (int i = t; i < 4096; i += 256) s += loss_part[i];
  red[t] = s;
  __syncthreads();
  for (int k = 128; k >= 1; k >>= 1) {
    if (t < k) red[t] += red[t + k];
    __syncthreads();
  }
  if (t == 0) out_loss[0] = red[0] * (1.f / 262144.f);
}

extern "C" void kernel_launch(void* const* d_in, const int* in_sizes, int n_in,
                              void* d_out, int out_size, void* d_ws, size_t ws_size,
                              hipStream_t stream) {
  (void)in_sizes; (void)n_in; (void)ws_size;
  const int* idx      = (const int*)d_in[0];
  const int* targets  = (const int*)d_in[1];
  const float* tok_emb = (const float*)d_in[2];
  const float* pos_emb = (const float*)d_in[3];
  const float* Wq = (const float*)d_in[4];
  const float* Wk = (const float*)d_in[5];
  const float* Wv = (const float*)d_in[6];
  const float* Wo = (const float*)d_in[7];
  const float* bo = (const float*)d_in[8];
  const float* ln1_g = (const float*)d_in[9];
  const float* ln1_b = (const float*)d_in[10];
  const float* ln2_g = (const float*)d_in[11];
  const float* ln2_b = (const float*)d_in[12];
  const float* W1 = (const float*)d_in[13];
  const float* b1 = (const float*)d_in[14];
  const float* W2 = (const float*)d_in[15];
  const float* b2 = (const float*)d_in[16];
  const float* lnf_g = (const float*)d_in[17];
  const float* lnf_b = (const float*)d_in[18];
  const float* lm_b = (const float*)d_in[19];

  short* wsb = (short*)d_ws;
  float* loss_part = (float*)((char*)d_ws + (size_t)WS_END * 2);
  float* out = (float*)d_out;

  prep_weights<<<1560, PREP_THR, 0, stream>>>(tok_emb, Wq, Wk, Wv, Wo, W1, W2, wsb);
  lm_forward<<<4096, 256, 0, stream>>>(idx, targets, tok_emb, pos_emb, bo,
                                       ln1_g, ln1_b, ln2_g, ln2_b, b1, b2,
                                       lnf_g, lnf_b, lm_b, wsb, out, loss_part);
  loss_reduce<<<1, 256, 0, stream>>>(loss_part, out + (out_size - 1));
}